// Round 1
// baseline (91.306 us; speedup 1.0000x reference)
//
#include <hip/hip_runtime.h>
#include <hip/hip_bf16.h>
#include <math.h>

#define T_DIM 256
#define C_DIM 128
#define H_DIM 64

typedef __attribute__((ext_vector_type(8))) short short8v;
typedef __attribute__((ext_vector_type(4))) short short4v;
typedef __attribute__((ext_vector_type(4))) float float4v;

// LDS layout (element = short/bf16):
//  Wt  [3][64][132]  @ 0       (25344 el)  weights transposed Wt[p][h][c], pad 132 for banks
//  Q   [256][68]     @ 25344   (17408 el)  Q[t][h], pad 68
//  K   [256][68]     @ 42752   (17408 el)
//  VT  [64][260]     @ 60160   (16640 el)  V transposed VT[h][t], pad 260
//  P   [8][32][17]   @ 76800   (4352 el)   per-wave P^T relayout buffer
//  total 81152 shorts = 162304 bytes (<= 160 KiB)
//  o_lds float[256][68] aliases Q+K exactly (byte 50688..120320) for output transpose
#define WT_OFF 0
#define Q_OFF 25344
#define K_OFF 42752
#define VT_OFF 60160
#define P_OFF 76800
#define SMEM_BYTES 162304

static __device__ __forceinline__ short f2bf(float f) {
  union { float f; unsigned u; } x; x.f = f;
  unsigned r = x.u + 0x7FFFu + ((x.u >> 16) & 1u);  // RNE
  return (short)(r >> 16);
}

static __device__ __forceinline__ short8v cat8(short4v a, short4v b) {
  short8v r;
  r[0] = a[0]; r[1] = a[1]; r[2] = a[2]; r[3] = a[3];
  r[4] = b[0]; r[5] = b[1]; r[6] = b[2]; r[7] = b[3];
  return r;
}

__global__ __launch_bounds__(512, 2) void head_fused(
    const float* __restrict__ x, const float* __restrict__ Wq,
    const float* __restrict__ Wk, const float* __restrict__ Wv,
    float* __restrict__ out)
{
  extern __shared__ __align__(16) short sm[];
  const int b   = blockIdx.x;
  const int tid = threadIdx.x;
  const int w   = tid >> 6;   // wave 0..7
  const int l   = tid & 63;   // lane
  const int il  = l & 15;     // lane&15
  const int g   = l >> 4;     // lane group 0..3

  // ---------- phase 0: stage W^T (bf16) into LDS ----------
  {
    const float* wlist[3] = {Wq, Wk, Wv};
#pragma unroll
    for (int p = 0; p < 3; ++p) {
      const float* Wp = wlist[p];
      for (int i4 = tid; i4 < 2048; i4 += 512) {   // 8192 f32 per W as float4
        float4v v = *(const float4v*)(Wp + i4 * 4);
        int c  = i4 >> 4;          // row of W (0..127)
        int h0 = (i4 & 15) * 4;    // col of W (0..60)
        int base = WT_OFF + p * 8448 + c;          // 8448 = 64*132
        sm[base + (h0 + 0) * 132] = f2bf(v.x);
        sm[base + (h0 + 1) * 132] = f2bf(v.y);
        sm[base + (h0 + 2) * 132] = f2bf(v.z);
        sm[base + (h0 + 3) * 132] = f2bf(v.w);
      }
    }
  }

  // x A-fragments for this wave's 32 rows (loaded before barrier; no LDS dep)
  const float* xb = x + (size_t)b * (T_DIM * C_DIM);
  short8v xa[2][4];
#pragma unroll
  for (int it2 = 0; it2 < 2; ++it2) {
    int t0 = w * 32 + it2 * 16;
#pragma unroll
    for (int ks = 0; ks < 4; ++ks) {
      const float* src = xb + (t0 + il) * C_DIM + ks * 32 + g * 8;
      float4v a0 = *(const float4v*)src;
      float4v a1 = *(const float4v*)(src + 4);
      short8v f;
      f[0] = f2bf(a0.x); f[1] = f2bf(a0.y); f[2] = f2bf(a0.z); f[3] = f2bf(a0.w);
      f[4] = f2bf(a1.x); f[5] = f2bf(a1.y); f[6] = f2bf(a1.z); f[7] = f2bf(a1.w);
      xa[it2][ks] = f;
    }
  }
  __syncthreads();

  // ---------- phase 1: projections Q,K,V ----------
#pragma unroll
  for (int p = 0; p < 3; ++p) {
#pragma unroll
    for (int ht = 0; ht < 4; ++ht) {
      float4v acc0 = {0.f, 0.f, 0.f, 0.f};
      float4v acc1 = {0.f, 0.f, 0.f, 0.f};
#pragma unroll
      for (int ks = 0; ks < 4; ++ks) {
        int e = WT_OFF + p * 8448 + (ht * 16 + il) * 132 + ks * 32 + g * 8;
        short8v wb = cat8(*(const short4v*)&sm[e], *(const short4v*)&sm[e + 4]);
        acc0 = __builtin_amdgcn_mfma_f32_16x16x32_bf16(xa[0][ks], wb, acc0, 0, 0, 0);
        acc1 = __builtin_amdgcn_mfma_f32_16x16x32_bf16(xa[1][ks], wb, acc1, 0, 0, 0);
      }
      if (p < 2) {
        // D-tile: lane holds [t = t0+g*4+r][h = ht*16+il]; write Q/K[t][h]
        int base = (p == 0 ? Q_OFF : K_OFF) + ht * 16 + il;
#pragma unroll
        for (int r = 0; r < 4; ++r) {
          sm[base + (w * 32 +      g * 4 + r) * 68] = f2bf(acc0[r]);
          sm[base + (w * 32 + 16 + g * 4 + r) * 68] = f2bf(acc1[r]);
        }
      } else {
        // V: write transposed VT[h][t]; r-consecutive t -> b64 packed writes
        int h = ht * 16 + il;
        short4v p0, p1;
#pragma unroll
        for (int r = 0; r < 4; ++r) { p0[r] = f2bf(acc0[r]); p1[r] = f2bf(acc1[r]); }
        *(short4v*)&sm[VT_OFF + h * 260 + w * 32 +      g * 4] = p0;
        *(short4v*)&sm[VT_OFF + h * 260 + w * 32 + 16 + g * 4] = p1;
      }
    }
  }
  __syncthreads();

  // ---------- phase 2: causal flash attention ----------
  // wave w handles query tiles {w, 15-w} (balanced causal work: 5 key-blocks each)
  const float SCL2 = 0.12751744f;  // C^-0.5 * log2(e)
  float4v oacc[2][4];
  int tqs[2]; tqs[0] = w; tqs[1] = 15 - w;
  const int pbase = P_OFF + w * 544;   // 544 = 32*17

#pragma unroll
  for (int tt = 0; tt < 2; ++tt) {
    const int tq    = tqs[tt];
    const int i_row = tq * 16 + il;    // this lane's query index
    // Q B-fragments (lane holds Q[i=il][h contiguous])
    short8v qf[2];
#pragma unroll
    for (int hk = 0; hk < 2; ++hk) {
      int e = Q_OFF + (tq * 16 + il) * 68 + hk * 32 + g * 8;
      qf[hk] = cat8(*(const short4v*)&sm[e], *(const short4v*)&sm[e + 4]);
    }
    float mr = -INFINITY, lr = 0.f;
    float4v oa0 = {0.f,0.f,0.f,0.f}, oa1 = oa0, oa2 = oa0, oa3 = oa0;
    const int nblk = (tq >> 2) + 1;
    for (int jb = 0; jb < nblk; ++jb) {
      // S^T = K . Q^T ; lane holds S^T[j = jb*64+jt*16+g*4+r][i = i_row]
      float s[4][4];
#pragma unroll
      for (int jt = 0; jt < 4; ++jt) {
        int e = K_OFF + (jb * 64 + jt * 16 + il) * 68 + g * 8;
        short8v kf0 = cat8(*(const short4v*)&sm[e],      *(const short4v*)&sm[e + 4]);
        short8v kf1 = cat8(*(const short4v*)&sm[e + 32], *(const short4v*)&sm[e + 36]);
        float4v a = {0.f, 0.f, 0.f, 0.f};
        a = __builtin_amdgcn_mfma_f32_16x16x32_bf16(kf0, qf[0], a, 0, 0, 0);
        a = __builtin_amdgcn_mfma_f32_16x16x32_bf16(kf1, qf[1], a, 0, 0, 0);
        s[jt][0] = a[0]; s[jt][1] = a[1]; s[jt][2] = a[2]; s[jt][3] = a[3];
      }
      // scale (in log2 domain) + causal mask
      const bool diag = (jb == (tq >> 2));
      float bm = -INFINITY;
#pragma unroll
      for (int jt = 0; jt < 4; ++jt)
#pragma unroll
        for (int r = 0; r < 4; ++r) {
          float v = s[jt][r] * SCL2;
          if (diag && (jb * 64 + jt * 16 + g * 4 + r) > i_row) v = -INFINITY;
          s[jt][r] = v;
          bm = fmaxf(bm, v);
        }
      // per-query reduce across the 4 lane-groups sharing i (lanes xor 16,32)
      bm = fmaxf(bm, __shfl_xor(bm, 16));
      bm = fmaxf(bm, __shfl_xor(bm, 32));
      const float mn = fmaxf(mr, bm);
      const float rs = exp2f(mr - mn);   // exp2(-inf)=0 on first block
      float tot = 0.f;
#pragma unroll
      for (int jt = 0; jt < 4; ++jt)
#pragma unroll
        for (int r = 0; r < 4; ++r) {
          float pv = exp2f(s[jt][r] - mn);
          s[jt][r] = pv;
          tot += pv;
        }
      tot += __shfl_xor(tot, 16);
      tot += __shfl_xor(tot, 32);
      lr = lr * rs + tot;
      mr = mn;
      oa0 *= rs; oa1 *= rs; oa2 *= rs; oa3 *= rs;

      // PV in two 32-key halves: P^T relayout via per-wave LDS, O^T = V^T . P^T
#pragma unroll
      for (int half = 0; half < 2; ++half) {
#pragma unroll
        for (int jt2 = 0; jt2 < 2; ++jt2)
#pragma unroll
          for (int r = 0; r < 4; ++r)
            sm[pbase + (jt2 * 16 + g * 4 + r) * 17 + il] = f2bf(s[half * 2 + jt2][r]);
        short8v pf;
#pragma unroll
        for (int jj = 0; jj < 8; ++jj)
          pf[jj] = sm[pbase + (g * 8 + jj) * 17 + il];
        const int cb = jb * 64 + half * 32 + g * 8;
        {
          int e = VT_OFF + (0 * 16 + il) * 260 + cb;
          short8v vf = cat8(*(const short4v*)&sm[e], *(const short4v*)&sm[e + 4]);
          oa0 = __builtin_amdgcn_mfma_f32_16x16x32_bf16(vf, pf, oa0, 0, 0, 0);
        }
        {
          int e = VT_OFF + (1 * 16 + il) * 260 + cb;
          short8v vf = cat8(*(const short4v*)&sm[e], *(const short4v*)&sm[e + 4]);
          oa1 = __builtin_amdgcn_mfma_f32_16x16x32_bf16(vf, pf, oa1, 0, 0, 0);
        }
        {
          int e = VT_OFF + (2 * 16 + il) * 260 + cb;
          short8v vf = cat8(*(const short4v*)&sm[e], *(const short4v*)&sm[e + 4]);
          oa2 = __builtin_amdgcn_mfma_f32_16x16x32_bf16(vf, pf, oa2, 0, 0, 0);
        }
        {
          int e = VT_OFF + (3 * 16 + il) * 260 + cb;
          short8v vf = cat8(*(const short4v*)&sm[e], *(const short4v*)&sm[e + 4]);
          oa3 = __builtin_amdgcn_mfma_f32_16x16x32_bf16(vf, pf, oa3, 0, 0, 0);
        }
      }
    }
    const float inv = 1.f / lr;
    oa0 *= inv; oa1 *= inv; oa2 *= inv; oa3 *= inv;
    oacc[tt][0] = oa0; oacc[tt][1] = oa1; oacc[tt][2] = oa2; oacc[tt][3] = oa3;
  }

  // ---------- phase 3: transpose O via LDS, coalesced store ----------
  __syncthreads();                       // everyone done reading Q/K
  float* olds = (float*)(sm + Q_OFF);    // aliases Q+K region, [256][68] f32
#pragma unroll
  for (int tt = 0; tt < 2; ++tt) {
    int i = tqs[tt] * 16 + il;
#pragma unroll
    for (int ht = 0; ht < 4; ++ht)
      *(float4v*)&olds[i * 68 + ht * 16 + g * 4] = oacc[tt][ht];
  }
  __syncthreads();
  float* outb = out + (size_t)b * (T_DIM * H_DIM);
#pragma unroll
  for (int k = 0; k < 8; ++k) {
    int idx = k * 512 + tid;             // 0..4095 float4s
    *(float4v*)(outb + idx * 4) = *(const float4v*)&olds[(idx >> 4) * 68 + (idx & 15) * 4];
  }
}

extern "C" void kernel_launch(void* const* d_in, const int* in_sizes, int n_in,
                              void* d_out, int out_size, void* d_ws, size_t ws_size,
                              hipStream_t stream) {
  const float* x  = (const float*)d_in[0];
  const float* Wq = (const float*)d_in[1];
  const float* Wk = (const float*)d_in[2];
  const float* Wv = (const float*)d_in[3];
  float* out = (float*)d_out;
  hipFuncSetAttribute((const void*)head_fused,
                      hipFuncAttributeMaxDynamicSharedMemorySize, SMEM_BYTES);
  head_fused<<<dim3(1024), dim3(512), SMEM_BYTES, stream>>>(x, Wq, Wk, Wv, out);
}